// Round 11
// baseline (3854.664 us; speedup 1.0000x reference)
//
#include <hip/hip_runtime.h>

#define N 4096
#define IN_DIM 128
#define T_STEPS 2048
#define KSLOTS 576           // uniform padded ELL row width; max nnz ~490 (mean 409.6, sd 19.2)
#define CHUNKS (KSLOTS / 64) // 9, uniform for all rows
#define NBLOCKS 128
#define NTHREADS 1024
#define ROWS_PER_WAVE 2
#define ROWS_PER_BLOCK (ROWS_PER_WAVE * (NTHREADS / 64))   // 32
#define SENTINEL_BITS 0x7FC00001u   // qNaN; h is always finite -> producers never write this

typedef float f32x4 __attribute__((ext_vector_type(4)));

// ---------------------------------------------------------------------------
// Kernel 0: fill out with the sentinel, write-through (agent scope) so it is
// at the coherence point before any step-kernel poll. Defends against 0xAA
// poison and stale floats from a previous replay (both non-sentinel).
// ---------------------------------------------------------------------------
__global__ void init_sentinel(float* __restrict__ out) {
    const size_t i = (size_t)blockIdx.x * blockDim.x + threadIdx.x;
    __hip_atomic_store(&out[i], __uint_as_float(SENTINEL_BITS),
                       __ATOMIC_RELAXED, __HIP_MEMORY_SCOPE_AGENT);
}

// ---------------------------------------------------------------------------
// Kernel 1: dense W -> uniform padded ELL with bank-aware chunk assignment
// (each 64-slot chunk hits every LDS bank ~2x; 2-way is free on gfx950).
// Padding: val=0, col=0 (same-address broadcast, free). Unchanged since R2.
// ---------------------------------------------------------------------------
__global__ void build_ell(const float* __restrict__ W,
                          float* __restrict__ vals,
                          unsigned short* __restrict__ cols) {
    __shared__ float sval[KSLOTS];
    __shared__ unsigned short scol[KSLOTS];
    __shared__ float slot_val[KSLOTS];
    __shared__ unsigned short slot_col[KSLOTS];
    __shared__ int chunk_fill[CHUNKS];
    __shared__ int cnt;

    const int r = blockIdx.x;
    const int tid = threadIdx.x;
    if (tid == 0) cnt = 0;
    if (tid < CHUNKS) chunk_fill[tid] = 0;
    __syncthreads();

    const float* wrow = W + (size_t)r * N;
    for (int j = tid; j < N; j += blockDim.x) {
        float w = wrow[j];
        if (w != 0.0f) {
            int p = atomicAdd(&cnt, 1);
            if (p < KSLOTS) { sval[p] = w; scol[p] = (unsigned short)j; }
        }
    }
    __syncthreads();
    for (int j = tid; j < KSLOTS; j += blockDim.x) { slot_val[j] = 0.0f; slot_col[j] = 0; }
    __syncthreads();

    if (tid < 32) {  // one thread per bank spreads its entries across chunks
        int k = 0;
        const int n = (cnt < KSLOTS) ? cnt : KSLOTS;
        for (int p = 0; p < n; ++p) {
            int c = scol[p];
            if ((c & 31) == tid) {
                int ch0 = (k + tid) % CHUNKS;
                for (int probe = 0; probe < CHUNKS; ++probe) {
                    int cc = ch0 + probe; if (cc >= CHUNKS) cc -= CHUNKS;
                    int pos = atomicAdd(&chunk_fill[cc], 1);
                    if (pos < 64) {
                        slot_val[cc * 64 + pos] = sval[p];
                        slot_col[cc * 64 + pos] = (unsigned short)c;
                        break;
                    }
                }
                ++k;
            }
        }
    }
    __syncthreads();

    float* vrow = vals + (size_t)r * KSLOTS;
    unsigned short* crow = cols + (size_t)r * KSLOTS;
    for (int j = tid; j < KSLOTS; j += blockDim.x) { vrow[j] = slot_val[j]; crow[j] = slot_col[j]; }
}

// ---------------------------------------------------------------------------
// Coherent 16B accesses straight at the coherence point (bypass L1+L2).
// Load form is R4/R9-proven (passed full harness incl. replay tripwires).
// ---------------------------------------------------------------------------
__device__ __forceinline__ f32x4 load_coherent_x4(const float* p) {
    f32x4 v;
    asm volatile("global_load_dwordx4 %0, %1, off sc0 sc1\n\t"
                 "s_waitcnt vmcnt(0)"
                 : "=v"(v) : "v"(p) : "memory");
    return v;
}

__device__ __forceinline__ void store_coherent_x4(float* p, f32x4 v) {
    asm volatile("global_store_dwordx4 %0, %1, off sc0 sc1"
                 :: "v"(p), "v"(v) : "memory");
}

__device__ __forceinline__ bool granule_not_ready(f32x4 hv) {
    return (__float_as_uint(hv.x) == SENTINEL_BITS) |
           (__float_as_uint(hv.y) == SENTINEL_BITS) |
           (__float_as_uint(hv.z) == SENTINEL_BITS) |
           (__float_as_uint(hv.w) == SENTINEL_BITS);
}

// Branch-free tanh (validated R6-first-launch + R9: absmax 3.9e-3 unchanged).
__device__ __forceinline__ float fast_tanh(float v) {
    float ax = __builtin_fabsf(v);
    float e  = __builtin_amdgcn_exp2f(ax * 2.88539008177793f);  // 2*log2(e)
    float r  = 1.0f - 2.0f * __builtin_amdgcn_rcpf(e + 1.0f);
    return __builtin_copysignf(r, v);
}

// ---------------------------------------------------------------------------
// R19: full 64-lane sum via the canonical GCN DPP ladder — row_shr 1/2/4/8
// then row_bcast15 (rows 1,3) and row_bcast31 (rows 2,3). Pure VALU: moves
// the reduction OFF the LDS pipe (shfl_xor = ds_bpermute on CDNA). Lane 63
// holds the total. bound_ctrl=true zero-fills invalid source lanes; masked
// rows keep old=0 so the add is a no-op there. All 64 lanes are active at
// the call sites (uniform control flow).
// ---------------------------------------------------------------------------
__device__ __forceinline__ float dpp_reduce_add(float v) {
    int t;
    t = __builtin_amdgcn_update_dpp(0, __float_as_int(v), 0x111, 0xf, 0xf, true); // shr:1
    v += __int_as_float(t);
    t = __builtin_amdgcn_update_dpp(0, __float_as_int(v), 0x112, 0xf, 0xf, true); // shr:2
    v += __int_as_float(t);
    t = __builtin_amdgcn_update_dpp(0, __float_as_int(v), 0x114, 0xf, 0xf, true); // shr:4
    v += __int_as_float(t);
    t = __builtin_amdgcn_update_dpp(0, __float_as_int(v), 0x118, 0xf, 0xf, true); // shr:8
    v += __int_as_float(t);
    t = __builtin_amdgcn_update_dpp(0, __float_as_int(v), 0x142, 0xa, 0xf, true); // bcast15
    v += __int_as_float(t);
    t = __builtin_amdgcn_update_dpp(0, __float_as_int(v), 0x143, 0xc, 0xf, true); // bcast31
    v += __int_as_float(t);
    return v;   // lane 63 = sum over all 64 lanes
}

// ---------------------------------------------------------------------------
// Kernel 2: persistent step kernel — R19 skeleton byte-identical (128 blocks,
// 2 rows/wave, qNaN data-as-flag, DPP reduce, x via cached global loads,
// hout collect, wave-0 full-line sc0 sc1 store). R20 single-variable change:
// poll ENTRY pacing. The initial s_sleep(8) (512cy) was calibrated for the
// pre-R19 ~1100cy compute phase; with R19's faster loop the first sample
// landed ~1212cy post-store-issue while the tail line is visible at ~700cy
// -> ~400-500cy alignment waste on the serial chain. New entry: s_sleep(2)
// (128cy), then the proven 1, 2, steady-4 ladder unchanged (steady-state
// traffic pacing untouched).
// ---------------------------------------------------------------------------
__global__ void __launch_bounds__(NTHREADS, 1) esn_steps(
    const float* __restrict__ x,
    const float* __restrict__ W_in,
    const float* __restrict__ vals,
    const unsigned short* __restrict__ cols,
    float* __restrict__ out) {

    __shared__ float h_lds[N];       // full previous state, 16 KB
    __shared__ __align__(16) float hout[ROWS_PER_BLOCK];  // block's 32 new rows

    const int tid  = threadIdx.x;
    const int lane = tid & 63;
    const int wave = tid >> 6;
    const int blockBase = blockIdx.x * ROWS_PER_BLOCK;
    const int base = blockBase + wave * ROWS_PER_WAVE;  // 2 rows/wave

    // Per-row W_in slices.
    float w0[ROWS_PER_WAVE], w1[ROWS_PER_WAVE];
    #pragma unroll
    for (int j = 0; j < ROWS_PER_WAVE; ++j) {
        w0[j] = W_in[(base + j) * IN_DIM + lane];
        w1[j] = W_in[(base + j) * IN_DIM + 64 + lane];
    }

    // Hoist the 2-row ELL slice into registers (18 vals + 18 byte offsets).
    float rv[ROWS_PER_WAVE][CHUNKS];
    int   rc[ROWS_PER_WAVE][CHUNKS];
    #pragma unroll
    for (int j = 0; j < ROWS_PER_WAVE; ++j) {
        const float* vp = vals + (size_t)(base + j) * KSLOTS;
        const unsigned short* cp = cols + (size_t)(base + j) * KSLOTS;
        #pragma unroll
        for (int i = 0; i < CHUNKS; ++i) {
            rv[j][i] = vp[(i << 6) + lane];
            rc[j][i] = ((int)cp[(i << 6) + lane]) << 2;
        }
    }

    const int i4 = tid << 2;

    for (int t = 0; t < T_STEPS; ++t) {
        // ---- x_t via cached global loads (L1 broadcast; issued before the
        //      poll so the latency hides under the ladder) ----
        const float xa = x[t * IN_DIM + lane];
        const float xb = x[t * IN_DIM + 64 + lane];

        // ---- stage h_{t-1}: paced coherent dwordx4 poll (R20 entry: 2) ----
        f32x4 hv;
        if (t > 0) {
            const float* addr = out + (size_t)(t - 1) * N + i4;
            __builtin_amdgcn_s_sleep(2);           // entry pacing (was 8 pre-R19)
            hv = load_coherent_x4(addr);
            if (granule_not_ready(hv)) {
                __builtin_amdgcn_s_sleep(1);
                hv = load_coherent_x4(addr);
                if (granule_not_ready(hv)) {
                    __builtin_amdgcn_s_sleep(2);
                    hv = load_coherent_x4(addr);
                    while (granule_not_ready(hv)) {
                        __builtin_amdgcn_s_sleep(4);   // steady 256cy cap
                        hv = load_coherent_x4(addr);
                    }
                }
            }
        } else {
            hv = (f32x4)(0.0f);
        }
        ((f32x4*)h_lds)[tid] = hv;
        __syncthreads();   // barrier 1: h_lds fully staged

        // ---- 2 row dots: input part + register-ELL sparse gather ----
        float acc[ROWS_PER_WAVE];
        #pragma unroll
        for (int j = 0; j < ROWS_PER_WAVE; ++j) acc[j] = w0[j] * xa + w1[j] * xb;

        #pragma unroll
        for (int j = 0; j < ROWS_PER_WAVE; ++j) {
            #pragma unroll
            for (int i = 0; i < CHUNKS; ++i) {
                acc[j] += rv[j][i] * *(const float*)((const char*)h_lds + rc[j][i]);
            }
        }

        // ---- DPP reduce (VALU pipe, not LDS): lane 63 holds both sums ----
        acc[0] = dpp_reduce_add(acc[0]);
        acc[1] = dpp_reduce_add(acc[1]);

        // lane 63 finalizes both rows into the LDS collect buffer
        if (lane == 63) {
            float hp0 = h_lds[base + 0];
            float hp1 = h_lds[base + 1];
            hout[wave * ROWS_PER_WAVE + 0] = 0.7f * hp0 + 0.3f * fast_tanh(acc[0]);
            hout[wave * ROWS_PER_WAVE + 1] = 0.7f * hp1 + 0.3f * fast_tanh(acc[1]);
        }
        __syncthreads();   // barrier 2: collect done + all h_lds reads done

        // ---- wave 0 emits the block's 32 rows as one coalesced 128B store;
        //      the other 15 waves proceed straight to the next step's poll ----
        if (tid < ROWS_PER_BLOCK / 4) {
            f32x4 hv4 = ((const f32x4*)hout)[tid];
            store_coherent_x4(out + (size_t)t * N + blockBase + (tid << 2), hv4);
        }
    }
}

// ---------------------------------------------------------------------------
// Workspace layout (bytes):
//   [0, +N*KSLOTS*4)       ELL vals (f32)   9.44 MB
//   [.., +N*KSLOTS*2)      ELL cols (u16)   4.72 MB
// ---------------------------------------------------------------------------
extern "C" void kernel_launch(void* const* d_in, const int* in_sizes, int n_in,
                              void* d_out, int out_size, void* d_ws, size_t ws_size,
                              hipStream_t stream) {
    const float* x    = (const float*)d_in[0];  // [2048,128]
    const float* W_in = (const float*)d_in[1];  // [4096,128]
    const float* W    = (const float*)d_in[2];  // [4096,4096]
    float* out = (float*)d_out;                 // [2048,4096]

    char* ws = (char*)d_ws;
    float* vals = (float*)ws;
    unsigned short* cols = (unsigned short*)(ws + (size_t)N * KSLOTS * 4);

    init_sentinel<<<(T_STEPS * N) / NTHREADS, NTHREADS, 0, stream>>>(out);
    build_ell<<<N, 256, 0, stream>>>(W, vals, cols);

    void* args[] = {(void*)&x, (void*)&W_in, (void*)&vals, (void*)&cols, (void*)&out};
    hipLaunchCooperativeKernel((void*)esn_steps, dim3(NBLOCKS), dim3(NTHREADS),
                               args, 0, stream);
}

// Round 12
// 3773.284 us; speedup vs baseline: 1.0216x; 1.0216x over previous
//
#include <hip/hip_runtime.h>

#define N 4096
#define IN_DIM 128
#define T_STEPS 2048
#define KSLOTS 576           // uniform padded ELL row width; max nnz ~490 (mean 409.6, sd 19.2)
#define CHUNKS (KSLOTS / 64) // 9 = worst-case chunks; mean needed = 6.93
#define NBLOCKS 128
#define NTHREADS 1024
#define ROWS_PER_WAVE 2
#define ROWS_PER_BLOCK (ROWS_PER_WAVE * (NTHREADS / 64))   // 32
#define SENTINEL_BITS 0x7FC00001u   // qNaN; h is always finite -> producers never write this

typedef float f32x4 __attribute__((ext_vector_type(4)));

// ---------------------------------------------------------------------------
// Kernel 0: fill out with the sentinel, write-through (agent scope) so it is
// at the coherence point before any step-kernel poll. Defends against 0xAA
// poison and stale floats from a previous replay (both non-sentinel).
// ---------------------------------------------------------------------------
__global__ void init_sentinel(float* __restrict__ out) {
    const size_t i = (size_t)blockIdx.x * blockDim.x + threadIdx.x;
    __hip_atomic_store(&out[i], __uint_as_float(SENTINEL_BITS),
                       __ATOMIC_RELAXED, __HIP_MEMORY_SCOPE_AGENT);
}

// ---------------------------------------------------------------------------
// Kernel 1: dense W -> ELL. R21 change: DENSITY-PACKED — each row's entries
// go into its leading nc = ceil(nnz/64) chunks (bank-rotation heuristic
// preserved, modulo nc instead of 9). nc is written to ncc[r]. Trailing
// chunks stay zero-filled (val=0, col=0), so a too-large count is always
// CORRECT (zero products) — the count only gates performance. If ncc==null
// (workspace too small), packing reverts to the R19 all-9 spread.
// ---------------------------------------------------------------------------
__global__ void build_ell(const float* __restrict__ W,
                          float* __restrict__ vals,
                          unsigned short* __restrict__ cols,
                          unsigned int* __restrict__ ncc) {
    __shared__ float sval[KSLOTS];
    __shared__ unsigned short scol[KSLOTS];
    __shared__ float slot_val[KSLOTS];
    __shared__ unsigned short slot_col[KSLOTS];
    __shared__ int chunk_fill[CHUNKS];
    __shared__ int cnt;

    const int r = blockIdx.x;
    const int tid = threadIdx.x;
    if (tid == 0) cnt = 0;
    if (tid < CHUNKS) chunk_fill[tid] = 0;
    __syncthreads();

    const float* wrow = W + (size_t)r * N;
    for (int j = tid; j < N; j += blockDim.x) {
        float w = wrow[j];
        if (w != 0.0f) {
            int p = atomicAdd(&cnt, 1);
            if (p < KSLOTS) { sval[p] = w; scol[p] = (unsigned short)j; }
        }
    }
    __syncthreads();
    for (int j = tid; j < KSLOTS; j += blockDim.x) { slot_val[j] = 0.0f; slot_col[j] = 0; }
    __syncthreads();

    const int total = (cnt < KSLOTS) ? cnt : KSLOTS;
    int nc = ncc ? ((total + 63) >> 6) : CHUNKS;   // capacity nc*64 >= total, exact
    if (nc < 1) nc = 1;
    if (nc > CHUNKS) nc = CHUNKS;

    if (tid < 32) {  // one thread per bank spreads its entries across nc chunks
        int k = 0;
        for (int p = 0; p < total; ++p) {
            int c = scol[p];
            if ((c & 31) == tid) {
                int ch0 = (k + tid) % nc;
                for (int probe = 0; probe < nc; ++probe) {
                    int cc = ch0 + probe; if (cc >= nc) cc -= nc;
                    int pos = atomicAdd(&chunk_fill[cc], 1);
                    if (pos < 64) {
                        slot_val[cc * 64 + pos] = sval[p];
                        slot_col[cc * 64 + pos] = (unsigned short)c;
                        break;
                    }
                }
                ++k;
            }
        }
    }
    __syncthreads();

    float* vrow = vals + (size_t)r * KSLOTS;
    unsigned short* crow = cols + (size_t)r * KSLOTS;
    for (int j = tid; j < KSLOTS; j += blockDim.x) { vrow[j] = slot_val[j]; crow[j] = slot_col[j]; }
    if (ncc && tid == 0) ncc[r] = (unsigned int)nc;
}

// ---------------------------------------------------------------------------
// Coherent 16B accesses straight at the coherence point (bypass L1+L2).
// Load form is R4/R9-proven (passed full harness incl. replay tripwires).
// ---------------------------------------------------------------------------
__device__ __forceinline__ f32x4 load_coherent_x4(const float* p) {
    f32x4 v;
    asm volatile("global_load_dwordx4 %0, %1, off sc0 sc1\n\t"
                 "s_waitcnt vmcnt(0)"
                 : "=v"(v) : "v"(p) : "memory");
    return v;
}

__device__ __forceinline__ void store_coherent_x4(float* p, f32x4 v) {
    asm volatile("global_store_dwordx4 %0, %1, off sc0 sc1"
                 :: "v"(p), "v"(v) : "memory");
}

__device__ __forceinline__ bool granule_not_ready(f32x4 hv) {
    return (__float_as_uint(hv.x) == SENTINEL_BITS) |
           (__float_as_uint(hv.y) == SENTINEL_BITS) |
           (__float_as_uint(hv.z) == SENTINEL_BITS) |
           (__float_as_uint(hv.w) == SENTINEL_BITS);
}

// Branch-free tanh (validated R6-first-launch + R9: absmax 3.9e-3 unchanged).
__device__ __forceinline__ float fast_tanh(float v) {
    float ax = __builtin_fabsf(v);
    float e  = __builtin_amdgcn_exp2f(ax * 2.88539008177793f);  // 2*log2(e)
    float r  = 1.0f - 2.0f * __builtin_amdgcn_rcpf(e + 1.0f);
    return __builtin_copysignf(r, v);
}

// ---------------------------------------------------------------------------
// R19: full 64-lane sum via the canonical GCN DPP ladder — row_shr 1/2/4/8
// then row_bcast15 (rows 1,3) and row_bcast31 (rows 2,3). Pure VALU: moves
// the reduction OFF the LDS pipe (shfl_xor = ds_bpermute on CDNA). Lane 63
// holds the total.
// ---------------------------------------------------------------------------
__device__ __forceinline__ float dpp_reduce_add(float v) {
    int t;
    t = __builtin_amdgcn_update_dpp(0, __float_as_int(v), 0x111, 0xf, 0xf, true); // shr:1
    v += __int_as_float(t);
    t = __builtin_amdgcn_update_dpp(0, __float_as_int(v), 0x112, 0xf, 0xf, true); // shr:2
    v += __int_as_float(t);
    t = __builtin_amdgcn_update_dpp(0, __float_as_int(v), 0x114, 0xf, 0xf, true); // shr:4
    v += __int_as_float(t);
    t = __builtin_amdgcn_update_dpp(0, __float_as_int(v), 0x118, 0xf, 0xf, true); // shr:8
    v += __int_as_float(t);
    t = __builtin_amdgcn_update_dpp(0, __float_as_int(v), 0x142, 0xa, 0xf, true); // bcast15
    v += __int_as_float(t);
    t = __builtin_amdgcn_update_dpp(0, __float_as_int(v), 0x143, 0xc, 0xf, true); // bcast31
    v += __int_as_float(t);
    return v;   // lane 63 = sum over all 64 lanes
}

// ---------------------------------------------------------------------------
// Kernel 2: persistent step kernel — R19 skeleton byte-identical (128 blocks,
// 2 rows/wave, qNaN data-as-flag, R13/R19 poll ladder entry sleep(8) — R20's
// earlier entry REGRESSED via extra miss-round fabric traffic — DPP reduce,
// x via cached global loads, hout collect, wave-0 full-line sc0 sc1 store).
// R21 change: the unrolled gather is gated per chunk by the row's packed
// chunk count (wave-uniform SGPR compare via readfirstlane). Mean 6.93 of 9
// chunks are real -> ~23% of gather ds_reads skipped, directly off the LDS
// pipe (the R19-validated bottleneck). Registers stay statically indexed.
// ---------------------------------------------------------------------------
__global__ void __launch_bounds__(NTHREADS, 1) esn_steps(
    const float* __restrict__ x,
    const float* __restrict__ W_in,
    const float* __restrict__ vals,
    const unsigned short* __restrict__ cols,
    float* __restrict__ out,
    const unsigned int* __restrict__ nccArr) {

    __shared__ float h_lds[N];       // full previous state, 16 KB
    __shared__ __align__(16) float hout[ROWS_PER_BLOCK];  // block's 32 new rows

    const int tid  = threadIdx.x;
    const int lane = tid & 63;
    const int wave = tid >> 6;
    const int blockBase = blockIdx.x * ROWS_PER_BLOCK;
    const int base = blockBase + wave * ROWS_PER_WAVE;  // 2 rows/wave

    // Per-row W_in slices.
    float w0[ROWS_PER_WAVE], w1[ROWS_PER_WAVE];
    #pragma unroll
    for (int j = 0; j < ROWS_PER_WAVE; ++j) {
        w0[j] = W_in[(base + j) * IN_DIM + lane];
        w1[j] = W_in[(base + j) * IN_DIM + 64 + lane];
    }

    // Hoist the 2-row ELL slice into registers (18 vals + 18 byte offsets).
    float rv[ROWS_PER_WAVE][CHUNKS];
    int   rc[ROWS_PER_WAVE][CHUNKS];
    #pragma unroll
    for (int j = 0; j < ROWS_PER_WAVE; ++j) {
        const float* vp = vals + (size_t)(base + j) * KSLOTS;
        const unsigned short* cp = cols + (size_t)(base + j) * KSLOTS;
        #pragma unroll
        for (int i = 0; i < CHUNKS; ++i) {
            rv[j][i] = vp[(i << 6) + lane];
            rc[j][i] = ((int)cp[(i << 6) + lane]) << 2;
        }
    }

    // Per-row packed chunk counts, forced wave-uniform into SGPRs.
    // (Counts only gate perf: trailing chunks are zero-filled, so any count
    //  up to CHUNKS is numerically identical.)
    int ncc0 = CHUNKS, ncc1 = CHUNKS;
    if (nccArr) {
        ncc0 = (int)nccArr[base + 0];
        ncc1 = (int)nccArr[base + 1];
    }
    ncc0 = __builtin_amdgcn_readfirstlane(ncc0);
    ncc1 = __builtin_amdgcn_readfirstlane(ncc1);

    const int i4 = tid << 2;

    for (int t = 0; t < T_STEPS; ++t) {
        // ---- x_t via cached global loads (L1 broadcast; issued before the
        //      poll so the latency hides under the ladder) ----
        const float xa = x[t * IN_DIM + lane];
        const float xb = x[t * IN_DIM + 64 + lane];

        // ---- stage h_{t-1}: R13/R19 paced coherent dwordx4 poll (proven) ----
        f32x4 hv;
        if (t > 0) {
            const float* addr = out + (size_t)(t - 1) * N + i4;
            __builtin_amdgcn_s_sleep(8);           // skip guaranteed-miss round
            hv = load_coherent_x4(addr);
            if (granule_not_ready(hv)) {
                __builtin_amdgcn_s_sleep(1);
                hv = load_coherent_x4(addr);
                if (granule_not_ready(hv)) {
                    __builtin_amdgcn_s_sleep(2);
                    hv = load_coherent_x4(addr);
                    while (granule_not_ready(hv)) {
                        __builtin_amdgcn_s_sleep(4);   // steady 256cy cap
                        hv = load_coherent_x4(addr);
                    }
                }
            }
        } else {
            hv = (f32x4)(0.0f);
        }
        ((f32x4*)h_lds)[tid] = hv;
        __syncthreads();   // barrier 1: h_lds fully staged

        // ---- 2 row dots: input part + count-gated register-ELL gather ----
        float acc[ROWS_PER_WAVE];
        #pragma unroll
        for (int j = 0; j < ROWS_PER_WAVE; ++j) acc[j] = w0[j] * xa + w1[j] * xb;

        #pragma unroll
        for (int i = 0; i < CHUNKS; ++i) {
            if (i < ncc0)
                acc[0] += rv[0][i] * *(const float*)((const char*)h_lds + rc[0][i]);
        }
        #pragma unroll
        for (int i = 0; i < CHUNKS; ++i) {
            if (i < ncc1)
                acc[1] += rv[1][i] * *(const float*)((const char*)h_lds + rc[1][i]);
        }

        // ---- DPP reduce (VALU pipe, not LDS): lane 63 holds both sums ----
        acc[0] = dpp_reduce_add(acc[0]);
        acc[1] = dpp_reduce_add(acc[1]);

        // lane 63 finalizes both rows into the LDS collect buffer
        if (lane == 63) {
            float hp0 = h_lds[base + 0];
            float hp1 = h_lds[base + 1];
            hout[wave * ROWS_PER_WAVE + 0] = 0.7f * hp0 + 0.3f * fast_tanh(acc[0]);
            hout[wave * ROWS_PER_WAVE + 1] = 0.7f * hp1 + 0.3f * fast_tanh(acc[1]);
        }
        __syncthreads();   // barrier 2: collect done + all h_lds reads done

        // ---- wave 0 emits the block's 32 rows as one coalesced 128B store;
        //      the other 15 waves proceed straight to the next step's poll ----
        if (tid < ROWS_PER_BLOCK / 4) {
            f32x4 hv4 = ((const f32x4*)hout)[tid];
            store_coherent_x4(out + (size_t)t * N + blockBase + (tid << 2), hv4);
        }
    }
}

// ---------------------------------------------------------------------------
// Workspace layout (bytes):
//   [0, +N*KSLOTS*4)       ELL vals (f32)   9.44 MB
//   [.., +N*KSLOTS*2)      ELL cols (u16)   4.72 MB
//   [.., +N*4)             per-row packed chunk counts (u32)  16 KB
// Host-side ws_size guard: if the count array doesn't fit, pass nullptr and
// both kernels revert to the exact R19 behavior (all-9 spread, no gating).
// ---------------------------------------------------------------------------
extern "C" void kernel_launch(void* const* d_in, const int* in_sizes, int n_in,
                              void* d_out, int out_size, void* d_ws, size_t ws_size,
                              hipStream_t stream) {
    const float* x    = (const float*)d_in[0];  // [2048,128]
    const float* W_in = (const float*)d_in[1];  // [4096,128]
    const float* W    = (const float*)d_in[2];  // [4096,4096]
    float* out = (float*)d_out;                 // [2048,4096]

    char* ws = (char*)d_ws;
    float* vals = (float*)ws;
    unsigned short* cols = (unsigned short*)(ws + (size_t)N * KSLOTS * 4);

    const size_t ell_bytes = (size_t)N * KSLOTS * 6;            // 14,155,776
    unsigned int* nccArr = (ws_size >= ell_bytes + (size_t)N * 4)
        ? (unsigned int*)(ws + ell_bytes) : nullptr;

    init_sentinel<<<(T_STEPS * N) / NTHREADS, NTHREADS, 0, stream>>>(out);
    build_ell<<<N, 256, 0, stream>>>(W, vals, cols, nccArr);

    void* args[] = {(void*)&x, (void*)&W_in, (void*)&vals, (void*)&cols,
                    (void*)&out, (void*)&nccArr};
    hipLaunchCooperativeKernel((void*)esn_steps, dim3(NBLOCKS), dim3(NTHREADS),
                               args, 0, stream);
}

// Round 13
// 3147.669 us; speedup vs baseline: 1.2246x; 1.1988x over previous
//
#include <hip/hip_runtime.h>

#define N 4096
#define IN_DIM 128
#define T_STEPS 2048
#define KSLOTS 576           // uniform padded ELL row width; max nnz ~490 (mean 409.6, sd 19.2)
#define CHUNKS (KSLOTS / 64) // 9, uniform for all rows (R21 packing REGRESSED: +11% conflicts)
#define NBLOCKS 256
#define NTHREADS 512
#define ROWS_PER_WAVE 2
#define ROWS_PER_BLOCK (ROWS_PER_WAVE * (NTHREADS / 64))   // 16
#define SENTINEL_BITS 0x7FC00001u   // qNaN; h is always finite -> producers never write this

typedef float f32x4 __attribute__((ext_vector_type(4)));

// ---------------------------------------------------------------------------
// Kernel 0: fill out with the sentinel, write-through (agent scope) so it is
// at the coherence point before any step-kernel poll. Defends against 0xAA
// poison and stale floats from a previous replay (both non-sentinel).
// ---------------------------------------------------------------------------
__global__ void init_sentinel(float* __restrict__ out) {
    const size_t i = (size_t)blockIdx.x * blockDim.x + threadIdx.x;
    __hip_atomic_store(&out[i], __uint_as_float(SENTINEL_BITS),
                       __ATOMIC_RELAXED, __HIP_MEMORY_SCOPE_AGENT);
}

// ---------------------------------------------------------------------------
// Kernel 1: dense W -> uniform padded ELL with bank-aware chunk assignment
// (each 64-slot chunk hits every LDS bank ~2x; 2-way is free on gfx950).
// Padding: val=0, col=0 (same-address broadcast, free). R19 version exactly —
// R21 taught that the zero-padding slots LOAD-BALANCE the banks (packing
// denser chunks raised conflicts 11%).
// ---------------------------------------------------------------------------
__global__ void build_ell(const float* __restrict__ W,
                          float* __restrict__ vals,
                          unsigned short* __restrict__ cols) {
    __shared__ float sval[KSLOTS];
    __shared__ unsigned short scol[KSLOTS];
    __shared__ float slot_val[KSLOTS];
    __shared__ unsigned short slot_col[KSLOTS];
    __shared__ int chunk_fill[CHUNKS];
    __shared__ int cnt;

    const int r = blockIdx.x;
    const int tid = threadIdx.x;
    if (tid == 0) cnt = 0;
    if (tid < CHUNKS) chunk_fill[tid] = 0;
    __syncthreads();

    const float* wrow = W + (size_t)r * N;
    for (int j = tid; j < N; j += blockDim.x) {
        float w = wrow[j];
        if (w != 0.0f) {
            int p = atomicAdd(&cnt, 1);
            if (p < KSLOTS) { sval[p] = w; scol[p] = (unsigned short)j; }
        }
    }
    __syncthreads();
    for (int j = tid; j < KSLOTS; j += blockDim.x) { slot_val[j] = 0.0f; slot_col[j] = 0; }
    __syncthreads();

    if (tid < 32) {  // one thread per bank spreads its entries across chunks
        int k = 0;
        const int n = (cnt < KSLOTS) ? cnt : KSLOTS;
        for (int p = 0; p < n; ++p) {
            int c = scol[p];
            if ((c & 31) == tid) {
                int ch0 = (k + tid) % CHUNKS;
                for (int probe = 0; probe < CHUNKS; ++probe) {
                    int cc = ch0 + probe; if (cc >= CHUNKS) cc -= CHUNKS;
                    int pos = atomicAdd(&chunk_fill[cc], 1);
                    if (pos < 64) {
                        slot_val[cc * 64 + pos] = sval[p];
                        slot_col[cc * 64 + pos] = (unsigned short)c;
                        break;
                    }
                }
                ++k;
            }
        }
    }
    __syncthreads();

    float* vrow = vals + (size_t)r * KSLOTS;
    unsigned short* crow = cols + (size_t)r * KSLOTS;
    for (int j = tid; j < KSLOTS; j += blockDim.x) { vrow[j] = slot_val[j]; crow[j] = slot_col[j]; }
}

// ---------------------------------------------------------------------------
// Coherent 16B accesses straight at the coherence point (bypass L1+L2).
// Single form is R4/R9-proven. The PAIRED form issues both loads back-to-back
// then waits ONCE — one RT per poll sample even though each thread now
// stages two granules (512-thread blocks must cover 16KB of h).
// ---------------------------------------------------------------------------
__device__ __forceinline__ f32x4 load_coherent_x4(const float* p) {
    f32x4 v;
    asm volatile("global_load_dwordx4 %0, %1, off sc0 sc1\n\t"
                 "s_waitcnt vmcnt(0)"
                 : "=v"(v) : "v"(p) : "memory");
    return v;
}

__device__ __forceinline__ void load_coherent_x4_pair(const float* p0, const float* p1,
                                                      f32x4* v0, f32x4* v1) {
    f32x4 a, b;
    asm volatile("global_load_dwordx4 %0, %2, off sc0 sc1\n\t"
                 "global_load_dwordx4 %1, %3, off sc0 sc1\n\t"
                 "s_waitcnt vmcnt(0)"
                 : "=v"(a), "=v"(b) : "v"(p0), "v"(p1) : "memory");
    *v0 = a; *v1 = b;
}

__device__ __forceinline__ void store_coherent_x4(float* p, f32x4 v) {
    asm volatile("global_store_dwordx4 %0, %1, off sc0 sc1"
                 :: "v"(p), "v"(v) : "memory");
}

__device__ __forceinline__ bool granule_not_ready(f32x4 hv) {
    return (__float_as_uint(hv.x) == SENTINEL_BITS) |
           (__float_as_uint(hv.y) == SENTINEL_BITS) |
           (__float_as_uint(hv.z) == SENTINEL_BITS) |
           (__float_as_uint(hv.w) == SENTINEL_BITS);
}

// Branch-free tanh (validated R6-first-launch + R9: absmax 3.9e-3 unchanged).
__device__ __forceinline__ float fast_tanh(float v) {
    float ax = __builtin_fabsf(v);
    float e  = __builtin_amdgcn_exp2f(ax * 2.88539008177793f);  // 2*log2(e)
    float r  = 1.0f - 2.0f * __builtin_amdgcn_rcpf(e + 1.0f);
    return __builtin_copysignf(r, v);
}

// ---------------------------------------------------------------------------
// R19: full 64-lane sum via the canonical GCN DPP ladder (pure VALU, off the
// LDS pipe). Lane 63 holds the total.
// ---------------------------------------------------------------------------
__device__ __forceinline__ float dpp_reduce_add(float v) {
    int t;
    t = __builtin_amdgcn_update_dpp(0, __float_as_int(v), 0x111, 0xf, 0xf, true); // shr:1
    v += __int_as_float(t);
    t = __builtin_amdgcn_update_dpp(0, __float_as_int(v), 0x112, 0xf, 0xf, true); // shr:2
    v += __int_as_float(t);
    t = __builtin_amdgcn_update_dpp(0, __float_as_int(v), 0x114, 0xf, 0xf, true); // shr:4
    v += __int_as_float(t);
    t = __builtin_amdgcn_update_dpp(0, __float_as_int(v), 0x118, 0xf, 0xf, true); // shr:8
    v += __int_as_float(t);
    t = __builtin_amdgcn_update_dpp(0, __float_as_int(v), 0x142, 0xa, 0xf, true); // bcast15
    v += __int_as_float(t);
    t = __builtin_amdgcn_update_dpp(0, __float_as_int(v), 0x143, 0xc, 0xf, true); // bcast31
    v += __int_as_float(t);
    return v;   // lane 63 = sum over all 64 lanes
}

// ---------------------------------------------------------------------------
// Kernel 2: persistent step kernel. R22 = R19's per-wave structure unchanged
// (2 rows/wave, 18-read gather, DPP reduce, x via cached global loads, qNaN
// data-as-flag, sleep(8)/1/2/steady-4 ladder) but 256 BLOCKS x 512 THREADS:
// the LDS pipe was the measured bottleneck (16 waves x 18 ds_read x 5.8cy +
// 415cy conflicts ~= 2085cy/step serialized per CU) and only 128/256 CUs
// were active. 8 waves/CU halves the gather serialization (~1040cy).
// Forced changes: each thread stages TWO granules (paired load, one RT);
// block output = 16 rows = one 64B aligned single-wave burst (sector-sized,
// NOT R12's scattered 16B trickle — WRITE_SIZE is the tripwire).
// ---------------------------------------------------------------------------
__global__ void __launch_bounds__(NTHREADS, 1) esn_steps(
    const float* __restrict__ x,
    const float* __restrict__ W_in,
    const float* __restrict__ vals,
    const unsigned short* __restrict__ cols,
    float* __restrict__ out) {

    __shared__ float h_lds[N];       // full previous state, 16 KB
    __shared__ __align__(16) float hout[ROWS_PER_BLOCK];  // block's 16 new rows

    const int tid  = threadIdx.x;
    const int lane = tid & 63;
    const int wave = tid >> 6;
    const int blockBase = blockIdx.x * ROWS_PER_BLOCK;
    const int base = blockBase + wave * ROWS_PER_WAVE;  // 2 rows/wave

    // Per-row W_in slices.
    float w0[ROWS_PER_WAVE], w1[ROWS_PER_WAVE];
    #pragma unroll
    for (int j = 0; j < ROWS_PER_WAVE; ++j) {
        w0[j] = W_in[(base + j) * IN_DIM + lane];
        w1[j] = W_in[(base + j) * IN_DIM + 64 + lane];
    }

    // Hoist the 2-row ELL slice into registers (18 vals + 18 byte offsets).
    float rv[ROWS_PER_WAVE][CHUNKS];
    int   rc[ROWS_PER_WAVE][CHUNKS];
    #pragma unroll
    for (int j = 0; j < ROWS_PER_WAVE; ++j) {
        const float* vp = vals + (size_t)(base + j) * KSLOTS;
        const unsigned short* cp = cols + (size_t)(base + j) * KSLOTS;
        #pragma unroll
        for (int i = 0; i < CHUNKS; ++i) {
            rv[j][i] = vp[(i << 6) + lane];
            rc[j][i] = ((int)cp[(i << 6) + lane]) << 2;
        }
    }

    const int i4 = tid << 2;                 // first granule: floats [4t, 4t+4)
    // second granule: floats [4t + 2048, ...): covered by thread t as well

    for (int t = 0; t < T_STEPS; ++t) {
        // ---- x_t via cached global loads (L1 broadcast; issued before the
        //      poll so the latency hides under the ladder) ----
        const float xa = x[t * IN_DIM + lane];
        const float xb = x[t * IN_DIM + 64 + lane];

        // ---- stage h_{t-1}: paced paired-granule coherent poll ----
        f32x4 hv0, hv1;
        if (t > 0) {
            const float* a0 = out + (size_t)(t - 1) * N + i4;
            const float* a1 = a0 + (NTHREADS * 4);   // +2048 floats
            __builtin_amdgcn_s_sleep(8);           // skip guaranteed-miss round
            load_coherent_x4_pair(a0, a1, &hv0, &hv1);
            if (granule_not_ready(hv0) | granule_not_ready(hv1)) {
                __builtin_amdgcn_s_sleep(1);
                load_coherent_x4_pair(a0, a1, &hv0, &hv1);
                if (granule_not_ready(hv0) | granule_not_ready(hv1)) {
                    __builtin_amdgcn_s_sleep(2);
                    load_coherent_x4_pair(a0, a1, &hv0, &hv1);
                    while (granule_not_ready(hv0) | granule_not_ready(hv1)) {
                        __builtin_amdgcn_s_sleep(4);   // steady 256cy cap
                        load_coherent_x4_pair(a0, a1, &hv0, &hv1);
                    }
                }
            }
        } else {
            hv0 = (f32x4)(0.0f);
            hv1 = (f32x4)(0.0f);
        }
        ((f32x4*)h_lds)[tid] = hv0;
        ((f32x4*)h_lds)[tid + NTHREADS] = hv1;
        __syncthreads();   // barrier 1: h_lds fully staged

        // ---- 2 row dots: input part + register-ELL sparse gather ----
        float acc[ROWS_PER_WAVE];
        #pragma unroll
        for (int j = 0; j < ROWS_PER_WAVE; ++j) acc[j] = w0[j] * xa + w1[j] * xb;

        #pragma unroll
        for (int j = 0; j < ROWS_PER_WAVE; ++j) {
            #pragma unroll
            for (int i = 0; i < CHUNKS; ++i) {
                acc[j] += rv[j][i] * *(const float*)((const char*)h_lds + rc[j][i]);
            }
        }

        // ---- DPP reduce (VALU pipe, not LDS): lane 63 holds both sums ----
        acc[0] = dpp_reduce_add(acc[0]);
        acc[1] = dpp_reduce_add(acc[1]);

        // lane 63 finalizes both rows into the LDS collect buffer
        if (lane == 63) {
            float hp0 = h_lds[base + 0];
            float hp1 = h_lds[base + 1];
            hout[wave * ROWS_PER_WAVE + 0] = 0.7f * hp0 + 0.3f * fast_tanh(acc[0]);
            hout[wave * ROWS_PER_WAVE + 1] = 0.7f * hp1 + 0.3f * fast_tanh(acc[1]);
        }
        __syncthreads();   // barrier 2: collect done + all h_lds reads done

        // ---- wave 0 lanes 0..3 emit the block's 16 rows as one aligned 64B
        //      burst (sector-sized, single wave, single moment) ----
        if (tid < ROWS_PER_BLOCK / 4) {
            f32x4 hv4 = ((const f32x4*)hout)[tid];
            store_coherent_x4(out + (size_t)t * N + blockBase + (tid << 2), hv4);
        }
    }
}

// ---------------------------------------------------------------------------
// Workspace layout (bytes):
//   [0, +N*KSLOTS*4)       ELL vals (f32)   9.44 MB
//   [.., +N*KSLOTS*2)      ELL cols (u16)   4.72 MB
// ---------------------------------------------------------------------------
extern "C" void kernel_launch(void* const* d_in, const int* in_sizes, int n_in,
                              void* d_out, int out_size, void* d_ws, size_t ws_size,
                              hipStream_t stream) {
    const float* x    = (const float*)d_in[0];  // [2048,128]
    const float* W_in = (const float*)d_in[1];  // [4096,128]
    const float* W    = (const float*)d_in[2];  // [4096,4096]
    float* out = (float*)d_out;                 // [2048,4096]

    char* ws = (char*)d_ws;
    float* vals = (float*)ws;
    unsigned short* cols = (unsigned short*)(ws + (size_t)N * KSLOTS * 4);

    init_sentinel<<<(T_STEPS * N) / 1024, 1024, 0, stream>>>(out);
    build_ell<<<N, 256, 0, stream>>>(W, vals, cols);

    void* args[] = {(void*)&x, (void*)&W_in, (void*)&vals, (void*)&cols, (void*)&out};
    hipLaunchCooperativeKernel((void*)esn_steps, dim3(NBLOCKS), dim3(NTHREADS),
                               args, 0, stream);
}